// Round 12
// baseline (1068.359 us; speedup 1.0000x reference)
//
#include <hip/hip_runtime.h>

// ============ ROUND 12: f32 output (the R11 discovery) + proven naive pipeline ============
// Edge buffer: int32 planar [src(E) | dst(E)] (C-order (2,E)); W row-major (in,out);
// output float32 [N][64] C-order. Pipeline identical to R8 (proven faithful).

__global__ void zero_i_k(int* p, int n) {
    int i = blockIdx.x * blockDim.x + threadIdx.x;
    if (i < n) p[i] = 0;
}

__global__ void count_k(const int* __restrict__ dst, int* __restrict__ deg, int E) {
    int e = blockIdx.x * blockDim.x + threadIdx.x;
    if (e < E) atomicAdd(&deg[dst[e]], 1);
}

__global__ void dinv_k(const int* __restrict__ deg, float* __restrict__ dinv, int n) {
    int i = blockIdx.x * blockDim.x + threadIdx.x;
    if (i < n) dinv[i] = rsqrtf((float)deg[i] + 1.0f);  // +1 self loop
}

// H[i][c] = sum_k X[i][k] * W[k][c]
__global__ void gemm_naive_k(const float* __restrict__ X, const float* __restrict__ W,
                             float* __restrict__ H, int n, int K, int C) {
    int tid = blockIdx.x * blockDim.x + threadIdx.x;
    if (tid >= n * C) return;
    int i = tid / C, c = tid - i * C;
    float s = 0.f;
    for (int k = 0; k < K; k++)
        s = fmaf(X[(size_t)i * K + k], W[(size_t)k * C + c], s);
    H[tid] = s;
}

// agg[i][c] = h[i][c] * dinv[i]^2   (self-loop term, initializes agg)
__global__ void selfinit_k(const float* __restrict__ h, const float* __restrict__ dinv,
                           float* __restrict__ agg, int n, int C) {
    int tid = blockIdx.x * blockDim.x + threadIdx.x;
    if (tid >= n * C) return;
    int i = tid / C;
    float di = dinv[i];
    agg[tid] = h[tid] * di * di;
}

// one block per edge: agg[dst][c] += h[src][c] * dinv[src]*dinv[dst]
__global__ void scatter_k(const int* __restrict__ src, const int* __restrict__ dst,
                          const float* __restrict__ dinv, const float* __restrict__ h,
                          float* __restrict__ agg, int C) {
    int e = blockIdx.x;
    int c = threadIdx.x;
    int s = src[e], d = dst[e];
    float w = dinv[s] * dinv[d];
    atomicAdd(&agg[(size_t)d * C + c], h[(size_t)s * C + c] * w);
}

__global__ void bias_relu_k(float* __restrict__ agg, const float* __restrict__ b,
                            int n, int C) {
    int tid = blockIdx.x * blockDim.x + threadIdx.x;
    if (tid >= n * C) return;
    int c = tid % C;
    agg[tid] = fmaxf(agg[tid] + b[c], 0.0f);
}

// f32 output store (R11 discovery: d_out is float*, reference output dtype f32)
__global__ void bias_out_k(const float* __restrict__ agg, const float* __restrict__ b,
                           float* __restrict__ out, int n, int C) {
    int tid = blockIdx.x * blockDim.x + threadIdx.x;
    if (tid >= n * C) return;
    int c = tid % C;
    out[tid] = agg[tid] + b[c];
}

extern "C" void kernel_launch(void* const* d_in, const int* in_sizes, int n_in,
                              void* d_out, int out_size, void* d_ws, size_t ws_size,
                              hipStream_t stream) {
    const float* x   = (const float*)d_in[0];   // f32 [N][128]
    const int*   ei  = (const int*)d_in[1];     // int32 planar [src(E) | dst(E)]
    const float* W1  = (const float*)d_in[2];   // f32 [128][128] (in,out)
    const float* b1  = (const float*)d_in[3];   // f32 [128]
    const float* W2  = (const float*)d_in[4];   // f32 [128][64]
    const float* b2  = (const float*)d_in[5];   // f32 [64]
    float* out = (float*)d_out;                 // f32 [N][64] C-order

    const int N = in_sizes[0] / 128;
    const int E = in_sizes[1] / 2;
    const int* src = ei;
    const int* dst = ei + E;

    char* p = (char*)d_ws;
    auto alloc = [&](size_t bytes) {
        char* q = p;
        p += (bytes + 255) & ~(size_t)255;
        return (void*)q;
    };
    int*   deg  = (int*)alloc((size_t)N * 4);
    float* dinv = (float*)alloc((size_t)N * 4);
    float* h1   = (float*)alloc((size_t)N * 128 * 4);   // 25.6 MB
    float* agg1 = (float*)alloc((size_t)N * 128 * 4);   // 25.6 MB
    float* h2   = h1;                                    // overlay: h1 dead after scatter1
    float* agg2 = h1 + (size_t)N * 64;                   // disjoint from h2

    const int nb   = (N + 255) / 256;
    const int neb  = (E + 255) / 256;
    const int n128 = (N * 128 + 255) / 256;
    const int n64  = (N * 64 + 255) / 256;

    // norm
    zero_i_k<<<nb, 256, 0, stream>>>(deg, N);
    count_k<<<neb, 256, 0, stream>>>(dst, deg, E);
    dinv_k<<<nb, 256, 0, stream>>>(deg, dinv, N);

    // layer 1
    gemm_naive_k<<<n128, 256, 0, stream>>>(x, W1, h1, N, 128, 128);
    selfinit_k<<<n128, 256, 0, stream>>>(h1, dinv, agg1, N, 128);
    scatter_k<<<E, 128, 0, stream>>>(src, dst, dinv, h1, agg1, 128);
    bias_relu_k<<<n128, 256, 0, stream>>>(agg1, b1, N, 128);

    // layer 2
    gemm_naive_k<<<n64, 256, 0, stream>>>(agg1, W2, h2, N, 128, 64);
    selfinit_k<<<n64, 256, 0, stream>>>(h2, dinv, agg2, N, 64);
    scatter_k<<<E, 64, 0, stream>>>(src, dst, dinv, h2, agg2, 64);
    bias_out_k<<<n64, 256, 0, stream>>>(agg2, b2, out, N, 64);
}

// Round 13
// 314.040 us; speedup vs baseline: 3.4020x; 3.4020x over previous
//
#include <hip/hip_runtime.h>

// ============ ROUND 13: CSR-gather aggregation + tiled GEMMs (all fp32) ============
// Passing baseline R12 (1068 us): scatter_k atomic-bound (VALUBusy 3%, 23% HBM).
// This round: R2's proven pipeline structure with the R11-discovered f32 output.
//   - CSR by dst (count/scan/fill; atomics only on 1.6M int ops)
//   - agg = per-node gather, fused self-loop init + bias (+ReLU); agg2 -> d_out direct
//   - GEMMs: LDS-tiled, float4 loads, 8x4 acc per thread

__global__ void zero_i_k(int* p, int n) {
    int i = blockIdx.x * blockDim.x + threadIdx.x;
    if (i < n) p[i] = 0;
}

__global__ void count_k(const int* __restrict__ dst, int* __restrict__ deg, int E) {
    int e = blockIdx.x * blockDim.x + threadIdx.x;
    if (e < E) atomicAdd(&deg[dst[e]], 1);
}

__global__ void dinv_k(const int* __restrict__ deg, float* __restrict__ dinv, int n) {
    int i = blockIdx.x * blockDim.x + threadIdx.x;
    if (i < n) dinv[i] = rsqrtf((float)deg[i] + 1.0f);  // +1 self loop
}

__global__ void scan_local_k(const int* __restrict__ cnt, int* __restrict__ excl,
                             int* __restrict__ bsums, int n) {
    __shared__ int s[256];
    int tid = threadIdx.x;
    int gid = blockIdx.x * 256 + tid;
    int v = (gid < n) ? cnt[gid] : 0;
    s[tid] = v;
    __syncthreads();
    for (int off = 1; off < 256; off <<= 1) {
        int t = (tid >= off) ? s[tid - off] : 0;
        __syncthreads();
        s[tid] += t;
        __syncthreads();
    }
    if (gid < n) excl[gid] = s[tid] - v;
    if (tid == 255) bsums[blockIdx.x] = s[255];
}

__global__ void scan_bsums_k(int* __restrict__ bsums, int nb) {
    __shared__ int s[256];
    int tid = threadIdx.x;
    int v = (tid < nb) ? bsums[tid] : 0;
    s[tid] = v;
    __syncthreads();
    for (int off = 1; off < 256; off <<= 1) {
        int t = (tid >= off) ? s[tid - off] : 0;
        __syncthreads();
        s[tid] += t;
        __syncthreads();
    }
    if (tid < nb) bsums[tid] = s[tid] - v;
}

__global__ void scan_add_k(int* __restrict__ row_start, const int* __restrict__ bsums,
                           int* __restrict__ cursor, int n, int E) {
    int gid = blockIdx.x * 256 + threadIdx.x;
    if (gid < n) {
        int rs = row_start[gid] + bsums[blockIdx.x];
        row_start[gid] = rs;
        cursor[gid] = rs;
    }
    if (gid == 0) row_start[n] = E;
}

__global__ void fill_k(const int* __restrict__ src, const int* __restrict__ dst,
                       int* __restrict__ cursor, int* __restrict__ csr_src, int E) {
    int e = blockIdx.x * blockDim.x + threadIdx.x;
    if (e < E) {
        int pos = atomicAdd(&cursor[dst[e]], 1);
        csr_src[pos] = src[e];
    }
}

// ---------------- GEMM1: h1[N][128] = x[N][128] @ W1[128][128], fp32 ----------------
// tile 64 rows x 128 cols, 256 threads, 8x4 acc/thread

__global__ __launch_bounds__(256) void gemm1_k(const float* __restrict__ X,
                                               const float* __restrict__ W,
                                               float* __restrict__ H, int n) {
    __shared__ float Ws[64][128];
    __shared__ float Xs[64][68];
    const int t = threadIdx.x;
    const int tx = t & 31, ty = t >> 5;
    const int row0 = blockIdx.x * 64;
    float acc[8][4] = {};
    for (int kc = 0; kc < 128; kc += 64) {
#pragma unroll
        for (int rep = 0; rep < 8; rep++) {
            int idx = rep * 1024 + t * 4;
            int k = idx >> 7, col = idx & 127;
            *reinterpret_cast<float4*>(&Ws[k][col]) =
                *reinterpret_cast<const float4*>(W + (kc + k) * 128 + col);
        }
#pragma unroll
        for (int rep = 0; rep < 4; rep++) {
            int idx = rep * 1024 + t * 4;
            int r = idx >> 6, cc = idx & 63;
            int grow = row0 + r;
            float4 v = make_float4(0.f, 0.f, 0.f, 0.f);
            if (grow < n) v = *reinterpret_cast<const float4*>(X + (size_t)grow * 128 + kc + cc);
            Xs[r][cc + 0] = v.x; Xs[r][cc + 1] = v.y; Xs[r][cc + 2] = v.z; Xs[r][cc + 3] = v.w;
        }
        __syncthreads();
#pragma unroll 8
        for (int k = 0; k < 64; k++) {
            float4 b = *reinterpret_cast<const float4*>(&Ws[k][tx * 4]);
#pragma unroll
            for (int i = 0; i < 8; i++) {
                float a = Xs[ty * 8 + i][k];
                acc[i][0] = fmaf(a, b.x, acc[i][0]);
                acc[i][1] = fmaf(a, b.y, acc[i][1]);
                acc[i][2] = fmaf(a, b.z, acc[i][2]);
                acc[i][3] = fmaf(a, b.w, acc[i][3]);
            }
        }
        __syncthreads();
    }
#pragma unroll
    for (int i = 0; i < 8; i++) {
        int r = row0 + ty * 8 + i;
        if (r < n)
            *reinterpret_cast<float4*>(H + (size_t)r * 128 + tx * 4) =
                make_float4(acc[i][0], acc[i][1], acc[i][2], acc[i][3]);
    }
}

// ---------------- GEMM2: h2[N][64] = agg1[N][128] @ W2[128][64], fp32 ----------------
// tile 128 rows x 64 cols, 256 threads, 8x4 acc/thread

__global__ __launch_bounds__(256) void gemm2_k(const float* __restrict__ X,
                                               const float* __restrict__ W,
                                               float* __restrict__ H, int n) {
    __shared__ float Ws[64][64];
    __shared__ float Xs[128][68];
    const int t = threadIdx.x;
    const int tx = t & 15, ty = t >> 4;
    const int row0 = blockIdx.x * 128;
    float acc[8][4] = {};
    for (int kc = 0; kc < 128; kc += 64) {
#pragma unroll
        for (int rep = 0; rep < 4; rep++) {
            int idx = rep * 1024 + t * 4;
            int k = idx >> 6, col = idx & 63;
            *reinterpret_cast<float4*>(&Ws[k][col]) =
                *reinterpret_cast<const float4*>(W + (kc + k) * 64 + col);
        }
#pragma unroll
        for (int rep = 0; rep < 8; rep++) {
            int idx = rep * 1024 + t * 4;
            int r = idx >> 6, cc = idx & 63;
            int grow = row0 + r;
            float4 v = make_float4(0.f, 0.f, 0.f, 0.f);
            if (grow < n) v = *reinterpret_cast<const float4*>(X + (size_t)grow * 128 + kc + cc);
            Xs[r][cc + 0] = v.x; Xs[r][cc + 1] = v.y; Xs[r][cc + 2] = v.z; Xs[r][cc + 3] = v.w;
        }
        __syncthreads();
#pragma unroll 8
        for (int k = 0; k < 64; k++) {
            float4 b = *reinterpret_cast<const float4*>(&Ws[k][tx * 4]);
#pragma unroll
            for (int i = 0; i < 8; i++) {
                float a = Xs[ty * 8 + i][k];
                acc[i][0] = fmaf(a, b.x, acc[i][0]);
                acc[i][1] = fmaf(a, b.y, acc[i][1]);
                acc[i][2] = fmaf(a, b.z, acc[i][2]);
                acc[i][3] = fmaf(a, b.w, acc[i][3]);
            }
        }
        __syncthreads();
    }
#pragma unroll
    for (int i = 0; i < 8; i++) {
        int r = row0 + ty * 8 + i;
        if (r < n)
            *reinterpret_cast<float4*>(H + (size_t)r * 64 + tx * 4) =
                make_float4(acc[i][0], acc[i][1], acc[i][2], acc[i][3]);
    }
}

// ---------------- Gather aggregation (fused self-loop + bias [+ReLU]) ----------------

__global__ __launch_bounds__(128) void agg1_k(const float* __restrict__ h,
                                              const int* __restrict__ row_start,
                                              const int* __restrict__ csr_src,
                                              const float* __restrict__ dinv,
                                              const float* __restrict__ bias,
                                              float* __restrict__ out, int n) {
    int i = blockIdx.x;
    int c = threadIdx.x;
    float di = dinv[i];
    float acc = h[(size_t)i * 128 + c] * di * di;   // self loop
    int j = row_start[i], e1 = row_start[i + 1];
    for (; j + 3 < e1; j += 4) {
        int s0 = csr_src[j], s1 = csr_src[j + 1], s2 = csr_src[j + 2], s3 = csr_src[j + 3];
        float w0 = dinv[s0] * di, w1 = dinv[s1] * di, w2 = dinv[s2] * di, w3 = dinv[s3] * di;
        float a0 = h[(size_t)s0 * 128 + c], a1 = h[(size_t)s1 * 128 + c];
        float a2 = h[(size_t)s2 * 128 + c], a3 = h[(size_t)s3 * 128 + c];
        acc = fmaf(a0, w0, acc); acc = fmaf(a1, w1, acc);
        acc = fmaf(a2, w2, acc); acc = fmaf(a3, w3, acc);
    }
    for (; j < e1; j++) {
        int s = csr_src[j];
        acc = fmaf(h[(size_t)s * 128 + c], dinv[s] * di, acc);
    }
    out[(size_t)i * 128 + c] = fmaxf(acc + bias[c], 0.0f);  // ReLU between layers
}

__global__ __launch_bounds__(64) void agg2_k(const float* __restrict__ h,
                                             const int* __restrict__ row_start,
                                             const int* __restrict__ csr_src,
                                             const float* __restrict__ dinv,
                                             const float* __restrict__ bias,
                                             float* __restrict__ out, int n) {
    int i = blockIdx.x;
    int c = threadIdx.x;
    float di = dinv[i];
    float acc = h[(size_t)i * 64 + c] * di * di;
    int j = row_start[i], e1 = row_start[i + 1];
    for (; j + 3 < e1; j += 4) {
        int s0 = csr_src[j], s1 = csr_src[j + 1], s2 = csr_src[j + 2], s3 = csr_src[j + 3];
        float w0 = dinv[s0] * di, w1 = dinv[s1] * di, w2 = dinv[s2] * di, w3 = dinv[s3] * di;
        float a0 = h[(size_t)s0 * 64 + c], a1 = h[(size_t)s1 * 64 + c];
        float a2 = h[(size_t)s2 * 64 + c], a3 = h[(size_t)s3 * 64 + c];
        acc = fmaf(a0, w0, acc); acc = fmaf(a1, w1, acc);
        acc = fmaf(a2, w2, acc); acc = fmaf(a3, w3, acc);
    }
    for (; j < e1; j++) {
        int s = csr_src[j];
        acc = fmaf(h[(size_t)s * 64 + c], dinv[s] * di, acc);
    }
    out[(size_t)i * 64 + c] = acc + bias[c];   // final layer: no ReLU, direct to d_out
}

// ---------------- launch ----------------

extern "C" void kernel_launch(void* const* d_in, const int* in_sizes, int n_in,
                              void* d_out, int out_size, void* d_ws, size_t ws_size,
                              hipStream_t stream) {
    const float* x   = (const float*)d_in[0];   // f32 [N][128]
    const int*   ei  = (const int*)d_in[1];     // int32 planar [src(E) | dst(E)]
    const float* W1  = (const float*)d_in[2];   // f32 [128][128]
    const float* b1  = (const float*)d_in[3];   // f32 [128]
    const float* W2  = (const float*)d_in[4];   // f32 [128][64]
    const float* b2  = (const float*)d_in[5];   // f32 [64]
    float* out = (float*)d_out;                 // f32 [N][64]

    const int N = in_sizes[0] / 128;
    const int E = in_sizes[1] / 2;
    const int* src = ei;
    const int* dst = ei + E;

    char* p = (char*)d_ws;
    auto alloc = [&](size_t bytes) {
        char* q = p;
        p += (bytes + 255) & ~(size_t)255;
        return (void*)q;
    };
    int*   deg       = (int*)alloc((size_t)N * 4);
    float* dinv      = (float*)alloc((size_t)N * 4);
    int*   row_start = (int*)alloc((size_t)(N + 1) * 4);
    int*   bsums     = (int*)alloc(1024);
    int*   cursor    = (int*)alloc((size_t)N * 4);
    int*   csr_src   = (int*)alloc((size_t)E * 4);
    float* h1        = (float*)alloc((size_t)N * 128 * 4);   // 25.6 MB
    float* agg1      = (float*)alloc((size_t)N * 128 * 4);   // 25.6 MB
    float* h2        = h1;   // reuse: h1 dead after agg1_k

    const int nb  = (N + 255) / 256;
    const int neb = (E + 255) / 256;

    // CSR + norm
    zero_i_k<<<nb, 256, 0, stream>>>(deg, N);
    count_k<<<neb, 256, 0, stream>>>(dst, deg, E);
    dinv_k<<<nb, 256, 0, stream>>>(deg, dinv, N);
    scan_local_k<<<nb, 256, 0, stream>>>(deg, row_start, bsums, N);
    scan_bsums_k<<<1, 256, 0, stream>>>(bsums, nb);
    scan_add_k<<<nb, 256, 0, stream>>>(row_start, bsums, cursor, N, E);
    fill_k<<<neb, 256, 0, stream>>>(src, dst, cursor, csr_src, E);

    // layer 1
    gemm1_k<<<(N + 63) / 64, 256, 0, stream>>>(x, W1, h1, N);
    agg1_k<<<N, 128, 0, stream>>>(h1, row_start, csr_src, dinv, b1, agg1, N);

    // layer 2
    gemm2_k<<<(N + 127) / 128, 256, 0, stream>>>(agg1, W2, h2, N);
    agg2_k<<<N, 64, 0, stream>>>(h2, row_start, csr_src, dinv, b2, out, N);
}

// Round 14
// 292.597 us; speedup vs baseline: 3.6513x; 1.0733x over previous
//
#include <hip/hip_runtime.h>
#include <hip/hip_bf16.h>

// ============ ROUND 14: bf16 intermediates + wave-per-node gather ============
// R13 (314 us): agg1_k #1 at 60 us, traffic-bound (hbm 46%, VALU 18%).
// Halve gather/GEMM-io bytes with bf16 h1/agg1/h2 (fp32 accum, f32 final out).

typedef unsigned short ushort_t;

__device__ __forceinline__ float bf2f(ushort_t u) {
    union { unsigned int i; float f; } v;
    v.i = ((unsigned int)u) << 16;
    return v.f;
}

__device__ __forceinline__ ushort_t f2bf(float f) {
    __hip_bfloat16 h = __float2bfloat16(f);
    return *reinterpret_cast<ushort_t*>(&h);
}

// ---------------- CSR build ----------------

__global__ void zero_i_k(int* p, int n) {
    int i = blockIdx.x * blockDim.x + threadIdx.x;
    if (i < n) p[i] = 0;
}

__global__ void count_k(const int* __restrict__ dst, int* __restrict__ deg, int E) {
    int e = blockIdx.x * blockDim.x + threadIdx.x;
    if (e < E) atomicAdd(&deg[dst[e]], 1);
}

// scan + fused dinv
__global__ void scan_local_k(const int* __restrict__ cnt, int* __restrict__ excl,
                             int* __restrict__ bsums, float* __restrict__ dinv, int n) {
    __shared__ int s[256];
    int tid = threadIdx.x;
    int gid = blockIdx.x * 256 + tid;
    int v = (gid < n) ? cnt[gid] : 0;
    if (gid < n) dinv[gid] = rsqrtf((float)v + 1.0f);  // +1 self loop
    s[tid] = v;
    __syncthreads();
    for (int off = 1; off < 256; off <<= 1) {
        int t = (tid >= off) ? s[tid - off] : 0;
        __syncthreads();
        s[tid] += t;
        __syncthreads();
    }
    if (gid < n) excl[gid] = s[tid] - v;
    if (tid == 255) bsums[blockIdx.x] = s[255];
}

__global__ void scan_bsums_k(int* __restrict__ bsums, int nb) {
    __shared__ int s[256];
    int tid = threadIdx.x;
    int v = (tid < nb) ? bsums[tid] : 0;
    s[tid] = v;
    __syncthreads();
    for (int off = 1; off < 256; off <<= 1) {
        int t = (tid >= off) ? s[tid - off] : 0;
        __syncthreads();
        s[tid] += t;
        __syncthreads();
    }
    if (tid < nb) bsums[tid] = s[tid] - v;
}

__global__ void scan_add_k(int* __restrict__ row_start, const int* __restrict__ bsums,
                           int* __restrict__ cursor, int n, int E) {
    int gid = blockIdx.x * 256 + threadIdx.x;
    if (gid < n) {
        int rs = row_start[gid] + bsums[blockIdx.x];
        row_start[gid] = rs;
        cursor[gid] = rs;
    }
    if (gid == 0) row_start[n] = E;
}

__global__ void fill_k(const int* __restrict__ src, const int* __restrict__ dst,
                       int* __restrict__ cursor, int* __restrict__ csr_src, int E) {
    int e = blockIdx.x * blockDim.x + threadIdx.x;
    if (e < E) {
        int pos = atomicAdd(&cursor[dst[e]], 1);
        csr_src[pos] = src[e];
    }
}

// ---------------- GEMM1: h1[N][128](bf16) = x[N][128](f32) @ W1[128][128](f32) ----------------

__global__ __launch_bounds__(256) void gemm1_k(const float* __restrict__ X,
                                               const float* __restrict__ W,
                                               ushort_t* __restrict__ H, int n) {
    __shared__ float Ws[64][128];
    __shared__ float Xs[64][68];
    const int t = threadIdx.x;
    const int tx = t & 31, ty = t >> 5;
    const int row0 = blockIdx.x * 64;
    float acc[8][4] = {};
    for (int kc = 0; kc < 128; kc += 64) {
#pragma unroll
        for (int rep = 0; rep < 8; rep++) {
            int idx = rep * 1024 + t * 4;
            int k = idx >> 7, col = idx & 127;
            *reinterpret_cast<float4*>(&Ws[k][col]) =
                *reinterpret_cast<const float4*>(W + (kc + k) * 128 + col);
        }
#pragma unroll
        for (int rep = 0; rep < 4; rep++) {
            int idx = rep * 1024 + t * 4;
            int r = idx >> 6, cc = idx & 63;
            int grow = row0 + r;
            float4 v = make_float4(0.f, 0.f, 0.f, 0.f);
            if (grow < n) v = *reinterpret_cast<const float4*>(X + (size_t)grow * 128 + kc + cc);
            Xs[r][cc + 0] = v.x; Xs[r][cc + 1] = v.y; Xs[r][cc + 2] = v.z; Xs[r][cc + 3] = v.w;
        }
        __syncthreads();
#pragma unroll 8
        for (int k = 0; k < 64; k++) {
            float4 b = *reinterpret_cast<const float4*>(&Ws[k][tx * 4]);
#pragma unroll
            for (int i = 0; i < 8; i++) {
                float a = Xs[ty * 8 + i][k];
                acc[i][0] = fmaf(a, b.x, acc[i][0]);
                acc[i][1] = fmaf(a, b.y, acc[i][1]);
                acc[i][2] = fmaf(a, b.z, acc[i][2]);
                acc[i][3] = fmaf(a, b.w, acc[i][3]);
            }
        }
        __syncthreads();
    }
#pragma unroll
    for (int i = 0; i < 8; i++) {
        int r = row0 + ty * 8 + i;
        if (r < n) {
            ushort4 o;
            o.x = f2bf(acc[i][0]); o.y = f2bf(acc[i][1]);
            o.z = f2bf(acc[i][2]); o.w = f2bf(acc[i][3]);
            *reinterpret_cast<ushort4*>(H + (size_t)r * 128 + tx * 4) = o;
        }
    }
}

// ---------------- GEMM2: h2[N][64](bf16) = agg1[N][128](bf16) @ W2[128][64](f32) ----------------

__global__ __launch_bounds__(256) void gemm2_k(const ushort_t* __restrict__ X,
                                               const float* __restrict__ W,
                                               ushort_t* __restrict__ H, int n) {
    __shared__ float Ws[64][64];
    __shared__ float Xs[128][68];
    const int t = threadIdx.x;
    const int tx = t & 15, ty = t >> 4;
    const int row0 = blockIdx.x * 128;
    float acc[8][4] = {};
    for (int kc = 0; kc < 128; kc += 64) {
#pragma unroll
        for (int rep = 0; rep < 4; rep++) {
            int idx = rep * 1024 + t * 4;
            int k = idx >> 6, col = idx & 63;
            *reinterpret_cast<float4*>(&Ws[k][col]) =
                *reinterpret_cast<const float4*>(W + (kc + k) * 64 + col);
        }
#pragma unroll
        for (int rep = 0; rep < 8; rep++) {
            int idx = rep * 1024 + t * 4;
            int r = idx >> 6, cc = idx & 63;
            int grow = row0 + r;
            float v0 = 0.f, v1 = 0.f, v2 = 0.f, v3 = 0.f;
            if (grow < n) {
                ushort4 x4 = *reinterpret_cast<const ushort4*>(X + (size_t)grow * 128 + kc + cc);
                v0 = bf2f(x4.x); v1 = bf2f(x4.y); v2 = bf2f(x4.z); v3 = bf2f(x4.w);
            }
            Xs[r][cc + 0] = v0; Xs[r][cc + 1] = v1; Xs[r][cc + 2] = v2; Xs[r][cc + 3] = v3;
        }
        __syncthreads();
#pragma unroll 8
        for (int k = 0; k < 64; k++) {
            float4 b = *reinterpret_cast<const float4*>(&Ws[k][tx * 4]);
#pragma unroll
            for (int i = 0; i < 8; i++) {
                float a = Xs[ty * 8 + i][k];
                acc[i][0] = fmaf(a, b.x, acc[i][0]);
                acc[i][1] = fmaf(a, b.y, acc[i][1]);
                acc[i][2] = fmaf(a, b.z, acc[i][2]);
                acc[i][3] = fmaf(a, b.w, acc[i][3]);
            }
        }
        __syncthreads();
    }
#pragma unroll
    for (int i = 0; i < 8; i++) {
        int r = row0 + ty * 8 + i;
        if (r < n) {
            ushort4 o;
            o.x = f2bf(acc[i][0]); o.y = f2bf(acc[i][1]);
            o.z = f2bf(acc[i][2]); o.w = f2bf(acc[i][3]);
            *reinterpret_cast<ushort4*>(H + (size_t)r * 64 + tx * 4) = o;
        }
    }
}

// ---------------- Aggregation: one wave per node ----------------
// agg1: C=128 bf16 rows (256 B). 64 lanes x ushort2 (4 B) = coalesced 256 B/row.

__global__ __launch_bounds__(64) void agg1_k(const ushort_t* __restrict__ h,
                                             const int* __restrict__ row_start,
                                             const int* __restrict__ csr_src,
                                             const float* __restrict__ dinv,
                                             const float* __restrict__ bias,
                                             ushort_t* __restrict__ out, int n) {
    int i = blockIdx.x;
    int c = threadIdx.x;           // lane owns channels {2c, 2c+1}
    float di = dinv[i];
    ushort2 sv = *reinterpret_cast<const ushort2*>(h + (size_t)i * 128 + 2 * c);
    float ax = bf2f(sv.x) * di * di;   // self loop
    float ay = bf2f(sv.y) * di * di;
    int j = row_start[i], e1 = row_start[i + 1];
    for (; j + 3 < e1; j += 4) {
        int s0 = csr_src[j], s1 = csr_src[j + 1], s2 = csr_src[j + 2], s3 = csr_src[j + 3];
        float w0 = dinv[s0] * di, w1 = dinv[s1] * di, w2 = dinv[s2] * di, w3 = dinv[s3] * di;
        ushort2 v0 = *reinterpret_cast<const ushort2*>(h + (size_t)s0 * 128 + 2 * c);
        ushort2 v1 = *reinterpret_cast<const ushort2*>(h + (size_t)s1 * 128 + 2 * c);
        ushort2 v2 = *reinterpret_cast<const ushort2*>(h + (size_t)s2 * 128 + 2 * c);
        ushort2 v3 = *reinterpret_cast<const ushort2*>(h + (size_t)s3 * 128 + 2 * c);
        ax = fmaf(bf2f(v0.x), w0, ax); ay = fmaf(bf2f(v0.y), w0, ay);
        ax = fmaf(bf2f(v1.x), w1, ax); ay = fmaf(bf2f(v1.y), w1, ay);
        ax = fmaf(bf2f(v2.x), w2, ax); ay = fmaf(bf2f(v2.y), w2, ay);
        ax = fmaf(bf2f(v3.x), w3, ax); ay = fmaf(bf2f(v3.y), w3, ay);
    }
    for (; j < e1; j++) {
        int s = csr_src[j];
        float w = dinv[s] * di;
        ushort2 v = *reinterpret_cast<const ushort2*>(h + (size_t)s * 128 + 2 * c);
        ax = fmaf(bf2f(v.x), w, ax); ay = fmaf(bf2f(v.y), w, ay);
    }
    ushort2 o;
    o.x = f2bf(fmaxf(ax + bias[2 * c], 0.0f));       // ReLU between layers
    o.y = f2bf(fmaxf(ay + bias[2 * c + 1], 0.0f));
    *reinterpret_cast<ushort2*>(out + (size_t)i * 128 + 2 * c) = o;
}

// agg2: C=64 bf16 rows (128 B). 64 lanes x ushort (2 B). Final out f32.

__global__ __launch_bounds__(64) void agg2_k(const ushort_t* __restrict__ h,
                                             const int* __restrict__ row_start,
                                             const int* __restrict__ csr_src,
                                             const float* __restrict__ dinv,
                                             const float* __restrict__ bias,
                                             float* __restrict__ out, int n) {
    int i = blockIdx.x;
    int c = threadIdx.x;
    float di = dinv[i];
    float acc = bf2f(h[(size_t)i * 64 + c]) * di * di;
    int j = row_start[i], e1 = row_start[i + 1];
    for (; j + 3 < e1; j += 4) {
        int s0 = csr_src[j], s1 = csr_src[j + 1], s2 = csr_src[j + 2], s3 = csr_src[j + 3];
        float w0 = dinv[s0] * di, w1 = dinv[s1] * di, w2 = dinv[s2] * di, w3 = dinv[s3] * di;
        float a0 = bf2f(h[(size_t)s0 * 64 + c]), a1 = bf2f(h[(size_t)s1 * 64 + c]);
        float a2 = bf2f(h[(size_t)s2 * 64 + c]), a3 = bf2f(h[(size_t)s3 * 64 + c]);
        acc = fmaf(a0, w0, acc); acc = fmaf(a1, w1, acc);
        acc = fmaf(a2, w2, acc); acc = fmaf(a3, w3, acc);
    }
    for (; j < e1; j++) {
        int s = csr_src[j];
        acc = fmaf(bf2f(h[(size_t)s * 64 + c]), dinv[s] * di, acc);
    }
    out[(size_t)i * 64 + c] = acc + bias[c];
}

// ---------------- launch ----------------

extern "C" void kernel_launch(void* const* d_in, const int* in_sizes, int n_in,
                              void* d_out, int out_size, void* d_ws, size_t ws_size,
                              hipStream_t stream) {
    const float* x   = (const float*)d_in[0];   // f32 [N][128]
    const int*   ei  = (const int*)d_in[1];     // int32 planar [src(E) | dst(E)]
    const float* W1  = (const float*)d_in[2];   // f32 [128][128]
    const float* b1  = (const float*)d_in[3];   // f32 [128]
    const float* W2  = (const float*)d_in[4];   // f32 [128][64]
    const float* b2  = (const float*)d_in[5];   // f32 [64]
    float* out = (float*)d_out;                 // f32 [N][64]

    const int N = in_sizes[0] / 128;
    const int E = in_sizes[1] / 2;
    const int* src = ei;
    const int* dst = ei + E;

    char* p = (char*)d_ws;
    auto alloc = [&](size_t bytes) {
        char* q = p;
        p += (bytes + 255) & ~(size_t)255;
        return (void*)q;
    };
    int*      deg       = (int*)alloc((size_t)N * 4);
    float*    dinv      = (float*)alloc((size_t)N * 4);
    int*      row_start = (int*)alloc((size_t)(N + 1) * 4);
    int*      bsums     = (int*)alloc(1024);
    int*      cursor    = (int*)alloc((size_t)N * 4);
    int*      csr_src   = (int*)alloc((size_t)E * 4);
    ushort_t* h1        = (ushort_t*)alloc((size_t)N * 128 * 2);  // 12.8 MB bf16
    ushort_t* agg1      = (ushort_t*)alloc((size_t)N * 128 * 2);  // 12.8 MB bf16
    ushort_t* h2        = h1;   // overlay: h1 dead after agg1_k

    const int nb  = (N + 255) / 256;
    const int neb = (E + 255) / 256;

    // CSR + norm
    zero_i_k<<<nb, 256, 0, stream>>>(deg, N);
    count_k<<<neb, 256, 0, stream>>>(dst, deg, E);
    scan_local_k<<<nb, 256, 0, stream>>>(deg, row_start, bsums, dinv, N);
    scan_bsums_k<<<1, 256, 0, stream>>>(bsums, nb);
    scan_add_k<<<nb, 256, 0, stream>>>(row_start, bsums, cursor, N, E);
    fill_k<<<neb, 256, 0, stream>>>(src, dst, cursor, csr_src, E);

    // layer 1
    gemm1_k<<<(N + 63) / 64, 256, 0, stream>>>(x, W1, h1, N);
    agg1_k<<<N, 64, 0, stream>>>(h1, row_start, csr_src, dinv, b1, agg1, N);

    // layer 2
    gemm2_k<<<(N + 127) / 128, 256, 0, stream>>>(agg1, W2, h2, N);
    agg2_k<<<N, 64, 0, stream>>>(h2, row_start, csr_src, dinv, b2, out, N);
}

// Round 15
// 248.634 us; speedup vs baseline: 4.2969x; 1.1768x over previous
//
#include <hip/hip_runtime.h>
#include <hip/hip_bf16.h>

// ============ ROUND 15: XCD-local CSR build (bucket multi-split) ============
// R14 (292 us): fill_k #1 at 55 us — WRITE_SIZE 52 MB for 3.2 MB of data (16x
// line amplification from cross-XCD scattered 4B stores). Rebuild CSR with
// bucket binning so every cacheline is written by one block: hist -> bscan ->
// bin (chunk-local runs) -> finalize (per-bucket reorder + deg/dinv/row_start).
// csr stored as uint16 (src < 65536). GEMM/agg unchanged from R14.

typedef unsigned short ushort_t;

__device__ __forceinline__ float bf2f(ushort_t u) {
    union { unsigned int i; float f; } v;
    v.i = ((unsigned int)u) << 16;
    return v.f;
}

__device__ __forceinline__ ushort_t f2bf(float f) {
    __hip_bfloat16 h = __float2bfloat16(f);
    return *reinterpret_cast<ushort_t*>(&h);
}

#define BMAX 512          // max buckets (N <= 65536 nodes, 128 nodes/bucket)
#define CHUNK 8192        // edges per bin_k work item

__global__ void zero_i_k(int* p, int n) {
    int i = blockIdx.x * blockDim.x + threadIdx.x;
    if (i < n) p[i] = 0;
}

// ---- A1: per-bucket histogram (LDS-aggregated) ----
__global__ __launch_bounds__(256) void hist_k(const int* __restrict__ dst,
                                              int* __restrict__ bucket_cnt, int E, int B) {
    __shared__ int h[BMAX];
    int tid = threadIdx.x;
    for (int i = tid; i < B; i += 256) h[i] = 0;
    __syncthreads();
    int stride = gridDim.x * 256;
    for (int e = blockIdx.x * 256 + tid; e < E; e += stride)
        atomicAdd(&h[dst[e] >> 7], 1);
    __syncthreads();
    for (int i = tid; i < B; i += 256)
        if (h[i]) atomicAdd(&bucket_cnt[i], h[i]);
}

// ---- A2: exclusive scan of bucket counts -> bucket_base, bucket_cursor ----
__global__ __launch_bounds__(512) void bscan_k(const int* __restrict__ bucket_cnt,
                                               int* __restrict__ bucket_base,
                                               int* __restrict__ bucket_cursor, int B, int E) {
    __shared__ int s[512];
    int tid = threadIdx.x;
    int v = (tid < B) ? bucket_cnt[tid] : 0;
    s[tid] = v;
    __syncthreads();
    for (int off = 1; off < 512; off <<= 1) {
        int t = (tid >= off) ? s[tid - off] : 0;
        __syncthreads();
        s[tid] += t;
        __syncthreads();
    }
    if (tid < B) {
        int ex = s[tid] - v;
        bucket_base[tid] = ex;
        bucket_cursor[tid] = ex;
    }
    if (tid == 0) bucket_base[B] = E;
}

// ---- A3: scatter edges into bucket regions, packed (src<<7)|dstLow ----
// Per (chunk,bucket): one global reservation, then a contiguous run written by
// this block only -> single-XCD lines, ~1.3x write amplification.
__global__ __launch_bounds__(256) void bin_k(const int* __restrict__ src,
                                             const int* __restrict__ dst,
                                             int* __restrict__ bucket_cursor,
                                             int* __restrict__ binned, int E) {
    __shared__ int lcnt[BMAX], lbase[BMAX], lcur[BMAX];
    int tid = threadIdx.x;
    int nchunks = (E + CHUNK - 1) / CHUNK;
    for (int ch = blockIdx.x; ch < nchunks; ch += gridDim.x) {
        int base = ch * CHUNK;
        int cnt = min(CHUNK, E - base);
        for (int i = tid; i < BMAX; i += 256) lcnt[i] = 0;
        __syncthreads();
        for (int k = tid; k < cnt; k += 256)
            atomicAdd(&lcnt[dst[base + k] >> 7], 1);
        __syncthreads();
        for (int i = tid; i < BMAX; i += 256) {
            int c = lcnt[i];
            if (c) lbase[i] = atomicAdd(&bucket_cursor[i], c);
            lcur[i] = 0;
        }
        __syncthreads();
        for (int k = tid; k < cnt; k += 256) {
            int d = dst[base + k];
            int b = d >> 7;
            int r = atomicAdd(&lcur[b], 1);
            binned[lbase[b] + r] = (src[base + k] << 7) | (d & 127);
        }
        __syncthreads();   // protect lcnt reuse next chunk
    }
}

// ---- B: per-bucket finalize: deg/dinv/row_start + in-bucket CSR reorder ----
__global__ __launch_bounds__(256) void finalize_k(const int* __restrict__ binned,
                                                  const int* __restrict__ bucket_base,
                                                  float* __restrict__ dinv,
                                                  int* __restrict__ row_start,
                                                  ushort_t* __restrict__ csr,
                                                  int N, int B, int E) {
    __shared__ int dcnt[128];   // per-node count, then reused as scatter cursor
    __shared__ int ebase[128];  // per-node exclusive offset within bucket
    __shared__ int sc[128];
    int b = blockIdx.x;
    int tid = threadIdx.x;
    int node0 = b << 7;
    int nn = min(128, N - node0);
    int e0 = bucket_base[b], e1 = bucket_base[b + 1];

    if (tid < 128) dcnt[tid] = 0;
    __syncthreads();
    for (int k = e0 + tid; k < e1; k += 256)
        atomicAdd(&dcnt[binned[k] & 127], 1);
    __syncthreads();
    if (tid < 128) sc[tid] = (tid < nn) ? dcnt[tid] : 0;
    __syncthreads();
    for (int off = 1; off < 128; off <<= 1) {
        int t = 0;
        if (tid < 128 && tid >= off) t = sc[tid - off];
        __syncthreads();
        if (tid < 128) sc[tid] += t;
        __syncthreads();
    }
    if (tid < nn) {
        int deg = dcnt[tid];
        int ex = sc[tid] - deg;
        ebase[tid] = ex;
        int g = node0 + tid;
        dinv[g] = rsqrtf((float)deg + 1.0f);   // +1 self loop
        row_start[g] = e0 + ex;
        dcnt[tid] = 0;                          // becomes cursor
    }
    if (tid == 0 && b == B - 1) row_start[N] = E;
    __syncthreads();
    for (int k = e0 + tid; k < e1; k += 256) {
        int e = binned[k];
        int low = e & 127;
        int r = atomicAdd(&dcnt[low], 1);
        csr[e0 + ebase[low] + r] = (ushort_t)((unsigned)e >> 7);
    }
}

// ---------------- GEMM1: h1[N][128](bf16) = x[N][128](f32) @ W1[128][128](f32) ----------------

__global__ __launch_bounds__(256) void gemm1_k(const float* __restrict__ X,
                                               const float* __restrict__ W,
                                               ushort_t* __restrict__ H, int n) {
    __shared__ float Ws[64][128];
    __shared__ float Xs[64][68];
    const int t = threadIdx.x;
    const int tx = t & 31, ty = t >> 5;
    const int row0 = blockIdx.x * 64;
    float acc[8][4] = {};
    for (int kc = 0; kc < 128; kc += 64) {
#pragma unroll
        for (int rep = 0; rep < 8; rep++) {
            int idx = rep * 1024 + t * 4;
            int k = idx >> 7, col = idx & 127;
            *reinterpret_cast<float4*>(&Ws[k][col]) =
                *reinterpret_cast<const float4*>(W + (kc + k) * 128 + col);
        }
#pragma unroll
        for (int rep = 0; rep < 4; rep++) {
            int idx = rep * 1024 + t * 4;
            int r = idx >> 6, cc = idx & 63;
            int grow = row0 + r;
            float4 v = make_float4(0.f, 0.f, 0.f, 0.f);
            if (grow < n) v = *reinterpret_cast<const float4*>(X + (size_t)grow * 128 + kc + cc);
            Xs[r][cc + 0] = v.x; Xs[r][cc + 1] = v.y; Xs[r][cc + 2] = v.z; Xs[r][cc + 3] = v.w;
        }
        __syncthreads();
#pragma unroll 8
        for (int k = 0; k < 64; k++) {
            float4 b = *reinterpret_cast<const float4*>(&Ws[k][tx * 4]);
#pragma unroll
            for (int i = 0; i < 8; i++) {
                float a = Xs[ty * 8 + i][k];
                acc[i][0] = fmaf(a, b.x, acc[i][0]);
                acc[i][1] = fmaf(a, b.y, acc[i][1]);
                acc[i][2] = fmaf(a, b.z, acc[i][2]);
                acc[i][3] = fmaf(a, b.w, acc[i][3]);
            }
        }
        __syncthreads();
    }
#pragma unroll
    for (int i = 0; i < 8; i++) {
        int r = row0 + ty * 8 + i;
        if (r < n) {
            ushort4 o;
            o.x = f2bf(acc[i][0]); o.y = f2bf(acc[i][1]);
            o.z = f2bf(acc[i][2]); o.w = f2bf(acc[i][3]);
            *reinterpret_cast<ushort4*>(H + (size_t)r * 128 + tx * 4) = o;
        }
    }
}

// ---------------- GEMM2: h2[N][64](bf16) = agg1[N][128](bf16) @ W2[128][64](f32) ----------------

__global__ __launch_bounds__(256) void gemm2_k(const ushort_t* __restrict__ X,
                                               const float* __restrict__ W,
                                               ushort_t* __restrict__ H, int n) {
    __shared__ float Ws[64][64];
    __shared__ float Xs[128][68];
    const int t = threadIdx.x;
    const int tx = t & 15, ty = t >> 4;
    const int row0 = blockIdx.x * 128;
    float acc[8][4] = {};
    for (int kc = 0; kc < 128; kc += 64) {
#pragma unroll
        for (int rep = 0; rep < 4; rep++) {
            int idx = rep * 1024 + t * 4;
            int k = idx >> 6, col = idx & 63;
            *reinterpret_cast<float4*>(&Ws[k][col]) =
                *reinterpret_cast<const float4*>(W + (kc + k) * 64 + col);
        }
#pragma unroll
        for (int rep = 0; rep < 8; rep++) {
            int idx = rep * 1024 + t * 4;
            int r = idx >> 6, cc = idx & 63;
            int grow = row0 + r;
            float v0 = 0.f, v1 = 0.f, v2 = 0.f, v3 = 0.f;
            if (grow < n) {
                ushort4 x4 = *reinterpret_cast<const ushort4*>(X + (size_t)grow * 128 + kc + cc);
                v0 = bf2f(x4.x); v1 = bf2f(x4.y); v2 = bf2f(x4.z); v3 = bf2f(x4.w);
            }
            Xs[r][cc + 0] = v0; Xs[r][cc + 1] = v1; Xs[r][cc + 2] = v2; Xs[r][cc + 3] = v3;
        }
        __syncthreads();
#pragma unroll 8
        for (int k = 0; k < 64; k++) {
            float4 b = *reinterpret_cast<const float4*>(&Ws[k][tx * 4]);
#pragma unroll
            for (int i = 0; i < 8; i++) {
                float a = Xs[ty * 8 + i][k];
                acc[i][0] = fmaf(a, b.x, acc[i][0]);
                acc[i][1] = fmaf(a, b.y, acc[i][1]);
                acc[i][2] = fmaf(a, b.z, acc[i][2]);
                acc[i][3] = fmaf(a, b.w, acc[i][3]);
            }
        }
        __syncthreads();
    }
#pragma unroll
    for (int i = 0; i < 8; i++) {
        int r = row0 + ty * 8 + i;
        if (r < n) {
            ushort4 o;
            o.x = f2bf(acc[i][0]); o.y = f2bf(acc[i][1]);
            o.z = f2bf(acc[i][2]); o.w = f2bf(acc[i][3]);
            *reinterpret_cast<ushort4*>(H + (size_t)r * 64 + tx * 4) = o;
        }
    }
}

// ---------------- Aggregation: one wave per node (csr = uint16) ----------------

__global__ __launch_bounds__(64) void agg1_k(const ushort_t* __restrict__ h,
                                             const int* __restrict__ row_start,
                                             const ushort_t* __restrict__ csr,
                                             const float* __restrict__ dinv,
                                             const float* __restrict__ bias,
                                             ushort_t* __restrict__ out, int n) {
    int i = blockIdx.x;
    int c = threadIdx.x;           // lane owns channels {2c, 2c+1}
    float di = dinv[i];
    ushort2 sv = *reinterpret_cast<const ushort2*>(h + (size_t)i * 128 + 2 * c);
    float ax = bf2f(sv.x) * di * di;   // self loop
    float ay = bf2f(sv.y) * di * di;
    int j = row_start[i], e1 = row_start[i + 1];
    for (; j + 3 < e1; j += 4) {
        int s0 = csr[j], s1 = csr[j + 1], s2 = csr[j + 2], s3 = csr[j + 3];
        float w0 = dinv[s0] * di, w1 = dinv[s1] * di, w2 = dinv[s2] * di, w3 = dinv[s3] * di;
        ushort2 v0 = *reinterpret_cast<const ushort2*>(h + (size_t)s0 * 128 + 2 * c);
        ushort2 v1 = *reinterpret_cast<const ushort2*>(h + (size_t)s1 * 128 + 2 * c);
        ushort2 v2 = *reinterpret_cast<const ushort2*>(h + (size_t)s2 * 128 + 2 * c);
        ushort2 v3 = *reinterpret_cast<const ushort2*>(h + (size_t)s3 * 128 + 2 * c);
        ax = fmaf(bf2f(v0.x), w0, ax); ay = fmaf(bf2f(v0.y), w0, ay);
        ax = fmaf(bf2f(v1.x), w1, ax); ay = fmaf(bf2f(v1.y), w1, ay);
        ax = fmaf(bf2f(v2.x), w2, ax); ay = fmaf(bf2f(v2.y), w2, ay);
        ax = fmaf(bf2f(v3.x), w3, ax); ay = fmaf(bf2f(v3.y), w3, ay);
    }
    for (; j < e1; j++) {
        int s = csr[j];
        float w = dinv[s] * di;
        ushort2 v = *reinterpret_cast<const ushort2*>(h + (size_t)s * 128 + 2 * c);
        ax = fmaf(bf2f(v.x), w, ax); ay = fmaf(bf2f(v.y), w, ay);
    }
    ushort2 o;
    o.x = f2bf(fmaxf(ax + bias[2 * c], 0.0f));       // ReLU between layers
    o.y = f2bf(fmaxf(ay + bias[2 * c + 1], 0.0f));
    *reinterpret_cast<ushort2*>(out + (size_t)i * 128 + 2 * c) = o;
}

__global__ __launch_bounds__(64) void agg2_k(const ushort_t* __restrict__ h,
                                             const int* __restrict__ row_start,
                                             const ushort_t* __restrict__ csr,
                                             const float* __restrict__ dinv,
                                             const float* __restrict__ bias,
                                             float* __restrict__ out, int n) {
    int i = blockIdx.x;
    int c = threadIdx.x;
    float di = dinv[i];
    float acc = bf2f(h[(size_t)i * 64 + c]) * di * di;
    int j = row_start[i], e1 = row_start[i + 1];
    for (; j + 3 < e1; j += 4) {
        int s0 = csr[j], s1 = csr[j + 1], s2 = csr[j + 2], s3 = csr[j + 3];
        float w0 = dinv[s0] * di, w1 = dinv[s1] * di, w2 = dinv[s2] * di, w3 = dinv[s3] * di;
        float a0 = bf2f(h[(size_t)s0 * 64 + c]), a1 = bf2f(h[(size_t)s1 * 64 + c]);
        float a2 = bf2f(h[(size_t)s2 * 64 + c]), a3 = bf2f(h[(size_t)s3 * 64 + c]);
        acc = fmaf(a0, w0, acc); acc = fmaf(a1, w1, acc);
        acc = fmaf(a2, w2, acc); acc = fmaf(a3, w3, acc);
    }
    for (; j < e1; j++) {
        int s = csr[j];
        acc = fmaf(bf2f(h[(size_t)s * 64 + c]), dinv[s] * di, acc);
    }
    out[(size_t)i * 64 + c] = acc + bias[c];
}

// ---------------- launch ----------------

extern "C" void kernel_launch(void* const* d_in, const int* in_sizes, int n_in,
                              void* d_out, int out_size, void* d_ws, size_t ws_size,
                              hipStream_t stream) {
    const float* x   = (const float*)d_in[0];   // f32 [N][128]
    const int*   ei  = (const int*)d_in[1];     // int32 planar [src(E) | dst(E)]
    const float* W1  = (const float*)d_in[2];   // f32 [128][128]
    const float* b1  = (const float*)d_in[3];   // f32 [128]
    const float* W2  = (const float*)d_in[4];   // f32 [128][64]
    const float* b2  = (const float*)d_in[5];   // f32 [64]
    float* out = (float*)d_out;                 // f32 [N][64]

    const int N = in_sizes[0] / 128;
    const int E = in_sizes[1] / 2;
    const int B = (N + 127) >> 7;               // 128-node buckets (<= BMAX)
    const int* src = ei;
    const int* dst = ei + E;

    char* p = (char*)d_ws;
    auto alloc = [&](size_t bytes) {
        char* q = p;
        p += (bytes + 255) & ~(size_t)255;
        return (void*)q;
    };
    int*      bucket_cnt    = (int*)alloc((size_t)BMAX * 4);
    int*      bucket_base   = (int*)alloc((size_t)(BMAX + 1) * 4);
    int*      bucket_cursor = (int*)alloc((size_t)BMAX * 4);
    float*    dinv          = (float*)alloc((size_t)N * 4);
    int*      row_start     = (int*)alloc((size_t)(N + 1) * 4);
    int*      binned        = (int*)alloc((size_t)E * 4);        // packed (src<<7)|dstLow
    ushort_t* csr           = (ushort_t*)alloc((size_t)E * 2);   // uint16 src
    ushort_t* h1            = (ushort_t*)alloc((size_t)N * 128 * 2);
    ushort_t* agg1          = (ushort_t*)alloc((size_t)N * 128 * 2);
    ushort_t* h2            = h1;   // overlay: h1 dead after agg1_k

    const int nchunks = (E + CHUNK - 1) / CHUNK;

    // CSR build (XCD-local writes)
    zero_i_k<<<(B + 255) / 256, 256, 0, stream>>>(bucket_cnt, B);
    hist_k<<<256, 256, 0, stream>>>(dst, bucket_cnt, E, B);
    bscan_k<<<1, 512, 0, stream>>>(bucket_cnt, bucket_base, bucket_cursor, B, E);
    bin_k<<<min(nchunks, 256), 256, 0, stream>>>(src, dst, bucket_cursor, binned, E);
    finalize_k<<<B, 256, 0, stream>>>(binned, bucket_base, dinv, row_start, csr, N, B, E);

    // layer 1
    gemm1_k<<<(N + 63) / 64, 256, 0, stream>>>(x, W1, h1, N);
    agg1_k<<<N, 64, 0, stream>>>(h1, row_start, csr, dinv, b1, agg1, N);

    // layer 2
    gemm2_k<<<(N + 127) / 128, 256, 0, stream>>>(agg1, W2, h2, N);
    agg2_k<<<N, 64, 0, stream>>>(h2, row_start, csr, dinv, b2, out, N);
}

// Round 16
// 228.306 us; speedup vs baseline: 4.6795x; 1.0890x over previous
//
#include <hip/hip_runtime.h>
#include <hip/hip_bf16.h>

// ============ ROUND 16: MFMA bf16 GEMMs (16x16x32), rest identical to R15 ============
// R15 (248.6 us): my top kernels ~130-150 us total; fp32 GEMMs ~45 us of it.
// Swap both GEMMs to bf16 MFMA with verified fragment layouts:
//   A[m=lane&15][k=(lane>>4)*8+j], B from n-major LDS (k-contiguous), C/D col=lane&15,
//   row=(lane>>4)*4+reg. K=128 in 4 MFMA steps. f32->bf16 staging in LDS.

typedef unsigned short ushort_t;
typedef __attribute__((ext_vector_type(8))) short bf16x8;
typedef __attribute__((ext_vector_type(4))) float f32x4;

__device__ __forceinline__ float bf2f(ushort_t u) {
    union { unsigned int i; float f; } v;
    v.i = ((unsigned int)u) << 16;
    return v.f;
}

__device__ __forceinline__ ushort_t f2bf(float f) {
    __hip_bfloat16 h = __float2bfloat16(f);
    return *reinterpret_cast<ushort_t*>(&h);
}

#define BMAX 512
#define CHUNK 8192

__global__ void zero_i_k(int* p, int n) {
    int i = blockIdx.x * blockDim.x + threadIdx.x;
    if (i < n) p[i] = 0;
}

// ---- CSR build (R15, unchanged) ----
__global__ __launch_bounds__(256) void hist_k(const int* __restrict__ dst,
                                              int* __restrict__ bucket_cnt, int E, int B) {
    __shared__ int h[BMAX];
    int tid = threadIdx.x;
    for (int i = tid; i < B; i += 256) h[i] = 0;
    __syncthreads();
    int stride = gridDim.x * 256;
    for (int e = blockIdx.x * 256 + tid; e < E; e += stride)
        atomicAdd(&h[dst[e] >> 7], 1);
    __syncthreads();
    for (int i = tid; i < B; i += 256)
        if (h[i]) atomicAdd(&bucket_cnt[i], h[i]);
}

__global__ __launch_bounds__(512) void bscan_k(const int* __restrict__ bucket_cnt,
                                               int* __restrict__ bucket_base,
                                               int* __restrict__ bucket_cursor, int B, int E) {
    __shared__ int s[512];
    int tid = threadIdx.x;
    int v = (tid < B) ? bucket_cnt[tid] : 0;
    s[tid] = v;
    __syncthreads();
    for (int off = 1; off < 512; off <<= 1) {
        int t = (tid >= off) ? s[tid - off] : 0;
        __syncthreads();
        s[tid] += t;
        __syncthreads();
    }
    if (tid < B) {
        int ex = s[tid] - v;
        bucket_base[tid] = ex;
        bucket_cursor[tid] = ex;
    }
    if (tid == 0) bucket_base[B] = E;
}

__global__ __launch_bounds__(256) void bin_k(const int* __restrict__ src,
                                             const int* __restrict__ dst,
                                             int* __restrict__ bucket_cursor,
                                             int* __restrict__ binned, int E) {
    __shared__ int lcnt[BMAX], lbase[BMAX], lcur[BMAX];
    int tid = threadIdx.x;
    int nchunks = (E + CHUNK - 1) / CHUNK;
    for (int ch = blockIdx.x; ch < nchunks; ch += gridDim.x) {
        int base = ch * CHUNK;
        int cnt = min(CHUNK, E - base);
        for (int i = tid; i < BMAX; i += 256) lcnt[i] = 0;
        __syncthreads();
        for (int k = tid; k < cnt; k += 256)
            atomicAdd(&lcnt[dst[base + k] >> 7], 1);
        __syncthreads();
        for (int i = tid; i < BMAX; i += 256) {
            int c = lcnt[i];
            if (c) lbase[i] = atomicAdd(&bucket_cursor[i], c);
            lcur[i] = 0;
        }
        __syncthreads();
        for (int k = tid; k < cnt; k += 256) {
            int d = dst[base + k];
            int b = d >> 7;
            int r = atomicAdd(&lcur[b], 1);
            binned[lbase[b] + r] = (src[base + k] << 7) | (d & 127);
        }
        __syncthreads();
    }
}

__global__ __launch_bounds__(256) void finalize_k(const int* __restrict__ binned,
                                                  const int* __restrict__ bucket_base,
                                                  float* __restrict__ dinv,
                                                  int* __restrict__ row_start,
                                                  ushort_t* __restrict__ csr,
                                                  int N, int B, int E) {
    __shared__ int dcnt[128];
    __shared__ int ebase[128];
    __shared__ int sc[128];
    int b = blockIdx.x;
    int tid = threadIdx.x;
    int node0 = b << 7;
    int nn = min(128, N - node0);
    int e0 = bucket_base[b], e1 = bucket_base[b + 1];

    if (tid < 128) dcnt[tid] = 0;
    __syncthreads();
    for (int k = e0 + tid; k < e1; k += 256)
        atomicAdd(&dcnt[binned[k] & 127], 1);
    __syncthreads();
    if (tid < 128) sc[tid] = (tid < nn) ? dcnt[tid] : 0;
    __syncthreads();
    for (int off = 1; off < 128; off <<= 1) {
        int t = 0;
        if (tid < 128 && tid >= off) t = sc[tid - off];
        __syncthreads();
        if (tid < 128) sc[tid] += t;
        __syncthreads();
    }
    if (tid < nn) {
        int deg = dcnt[tid];
        int ex = sc[tid] - deg;
        ebase[tid] = ex;
        int g = node0 + tid;
        dinv[g] = rsqrtf((float)deg + 1.0f);
        row_start[g] = e0 + ex;
        dcnt[tid] = 0;
    }
    if (tid == 0 && b == B - 1) row_start[N] = E;
    __syncthreads();
    for (int k = e0 + tid; k < e1; k += 256) {
        int e = binned[k];
        int low = e & 127;
        int r = atomicAdd(&dcnt[low], 1);
        csr[e0 + ebase[low] + r] = (ushort_t)((unsigned)e >> 7);
    }
}

// ---------------- GEMM1 (MFMA): h1[N][128](bf16) = x(f32) @ W1(f32) ----------------
// block 256 = 4 waves; tile 64 rows x 128 cols; K=128 one shot (4 MFMA ksteps).

__global__ __launch_bounds__(256) void gemm1_k(const float* __restrict__ X,
                                               const float* __restrict__ W,
                                               ushort_t* __restrict__ H, int n) {
    __shared__ ushort_t As[64][136];   // [m][k] bf16, pad 8
    __shared__ ushort_t Bt[128][136];  // [n][k] bf16 (W transposed), pad 8
    const int t = threadIdx.x;
    const int row0 = blockIdx.x * 64;
    // stage A (64x128 f32 -> bf16)
#pragma unroll
    for (int rep = 0; rep < 8; rep++) {
        int idx = rep * 1024 + t * 4;
        int r = idx >> 7, c = idx & 127;
        int gr = row0 + r;
        float4 v = make_float4(0.f, 0.f, 0.f, 0.f);
        if (gr < n) v = *reinterpret_cast<const float4*>(X + (size_t)gr * 128 + c);
        As[r][c + 0] = f2bf(v.x); As[r][c + 1] = f2bf(v.y);
        As[r][c + 2] = f2bf(v.z); As[r][c + 3] = f2bf(v.w);
    }
    // stage B transposed (W[k][n] f32 -> Bt[n][k] bf16)
#pragma unroll
    for (int rep = 0; rep < 16; rep++) {
        int idx = rep * 1024 + t * 4;
        int k = idx >> 7, nn = idx & 127;
        float4 v = *reinterpret_cast<const float4*>(W + k * 128 + nn);
        Bt[nn + 0][k] = f2bf(v.x); Bt[nn + 1][k] = f2bf(v.y);
        Bt[nn + 2][k] = f2bf(v.z); Bt[nn + 3][k] = f2bf(v.w);
    }
    __syncthreads();
    const int lane = t & 63;
    const int wave = t >> 6;           // wave owns rows [wave*16, wave*16+16)
    const int l15 = lane & 15;
    const int koff = (lane >> 4) * 8;  // k-octet within K=32 step
    f32x4 acc[8] = {};                 // 8 col-tiles of 16
#pragma unroll
    for (int ks = 0; ks < 4; ks++) {
        int kb = ks * 32 + koff;
        bf16x8 a = *reinterpret_cast<const bf16x8*>(&As[wave * 16 + l15][kb]);
#pragma unroll
        for (int tc = 0; tc < 8; tc++) {
            bf16x8 b = *reinterpret_cast<const bf16x8*>(&Bt[tc * 16 + l15][kb]);
            acc[tc] = __builtin_amdgcn_mfma_f32_16x16x32_bf16(a, b, acc[tc], 0, 0, 0);
        }
    }
    // C/D: col = lane&15, row = (lane>>4)*4 + reg
    const int rbase = row0 + wave * 16 + (lane >> 4) * 4;
#pragma unroll
    for (int reg = 0; reg < 4; reg++) {
        int gr = rbase + reg;
        if (gr < n) {
#pragma unroll
            for (int tc = 0; tc < 8; tc++)
                H[(size_t)gr * 128 + tc * 16 + l15] = f2bf(acc[tc][reg]);
        }
    }
}

// ---------------- GEMM2 (MFMA): h2[N][64](bf16) = agg1(bf16) @ W2(f32) ----------------
// block 256 = 4 waves; tile 64 rows x 64 cols; K=128.

__global__ __launch_bounds__(256) void gemm2_k(const ushort_t* __restrict__ X,
                                               const float* __restrict__ W,
                                               ushort_t* __restrict__ H, int n) {
    __shared__ ushort_t As[64][136];
    __shared__ ushort_t Bt[64][136];
    const int t = threadIdx.x;
    const int row0 = blockIdx.x * 64;
    // stage A (bf16 direct copy)
#pragma unroll
    for (int rep = 0; rep < 8; rep++) {
        int idx = rep * 1024 + t * 4;
        int r = idx >> 7, c = idx & 127;
        int gr = row0 + r;
        ushort4 v = make_ushort4(0, 0, 0, 0);
        if (gr < n) v = *reinterpret_cast<const ushort4*>(X + (size_t)gr * 128 + c);
        As[r][c + 0] = v.x; As[r][c + 1] = v.y; As[r][c + 2] = v.z; As[r][c + 3] = v.w;
    }
    // stage B transposed (W2[k][64] f32 -> Bt[n][k] bf16)
#pragma unroll
    for (int rep = 0; rep < 8; rep++) {
        int idx = rep * 1024 + t * 4;
        int k = idx >> 6, nn = idx & 63;
        float4 v = *reinterpret_cast<const float4*>(W + k * 64 + nn);
        Bt[nn + 0][k] = f2bf(v.x); Bt[nn + 1][k] = f2bf(v.y);
        Bt[nn + 2][k] = f2bf(v.z); Bt[nn + 3][k] = f2bf(v.w);
    }
    __syncthreads();
    const int lane = t & 63;
    const int wave = t >> 6;
    const int l15 = lane & 15;
    const int koff = (lane >> 4) * 8;
    f32x4 acc[4] = {};
#pragma unroll
    for (int ks = 0; ks < 4; ks++) {
        int kb = ks * 32 + koff;
        bf16x8 a = *reinterpret_cast<const bf16x8*>(&As[wave * 16 + l15][kb]);
#pragma unroll
        for (int tc = 0; tc < 4; tc++) {
            bf16x8 b = *reinterpret_cast<const bf16x8*>(&Bt[tc * 16 + l15][kb]);
            acc[tc] = __builtin_amdgcn_mfma_f32_16x16x32_bf16(a, b, acc[tc], 0, 0, 0);
        }
    }
    const int rbase = row0 + wave * 16 + (lane >> 4) * 4;
#pragma unroll
    for (int reg = 0; reg < 4; reg++) {
        int gr = rbase + reg;
        if (gr < n) {
#pragma unroll
            for (int tc = 0; tc < 4; tc++)
                H[(size_t)gr * 64 + tc * 16 + l15] = f2bf(acc[tc][reg]);
        }
    }
}

// ---------------- Aggregation (R15, unchanged) ----------------

__global__ __launch_bounds__(64) void agg1_k(const ushort_t* __restrict__ h,
                                             const int* __restrict__ row_start,
                                             const ushort_t* __restrict__ csr,
                                             const float* __restrict__ dinv,
                                             const float* __restrict__ bias,
                                             ushort_t* __restrict__ out, int n) {
    int i = blockIdx.x;
    int c = threadIdx.x;
    float di = dinv[i];
    ushort2 sv = *reinterpret_cast<const ushort2*>(h + (size_t)i * 128 + 2 * c);
    float ax = bf2f(sv.x) * di * di;
    float ay = bf2f(sv.y) * di * di;
    int j = row_start[i], e1 = row_start[i + 1];
    for (; j + 3 < e1; j += 4) {
        int s0 = csr[j], s1 = csr[j + 1], s2 = csr[j + 2], s3 = csr[j + 3];
        float w0 = dinv[s0] * di, w1 = dinv[s1] * di, w2 = dinv[s2] * di, w3 = dinv[s3] * di;
        ushort2 v0 = *reinterpret_cast<const ushort2*>(h + (size_t)s0 * 128 + 2 * c);
        ushort2 v1 = *reinterpret_cast<const ushort2*>(h + (size_t)s1 * 128 + 2 * c);
        ushort2 v2 = *reinterpret_cast<const ushort2*>(h + (size_t)s2 * 128 + 2 * c);
        ushort2 v3 = *reinterpret_cast<const ushort2*>(h + (size_t)s3 * 128 + 2 * c);
        ax = fmaf(bf2f(v0.x), w0, ax); ay = fmaf(bf2f(v0.y), w0, ay);
        ax = fmaf(bf2f(v1.x), w1, ax); ay = fmaf(bf2f(v1.y), w1, ay);
        ax = fmaf(bf2f(v2.x), w2, ax); ay = fmaf(bf2f(v2.y), w2, ay);
        ax = fmaf(bf2f(v3.x), w3, ax); ay = fmaf(bf2f(v3.y), w3, ay);
    }
    for (; j < e1; j++) {
        int s = csr[j];
        float w = dinv[s] * di;
        ushort2 v = *reinterpret_cast<const ushort2*>(h + (size_t)s * 128 + 2 * c);
        ax = fmaf(bf2f(v.x), w, ax); ay = fmaf(bf2f(v.y), w, ay);
    }
    ushort2 o;
    o.x = f2bf(fmaxf(ax + bias[2 * c], 0.0f));
    o.y = f2bf(fmaxf(ay + bias[2 * c + 1], 0.0f));
    *reinterpret_cast<ushort2*>(out + (size_t)i * 128 + 2 * c) = o;
}

__global__ __launch_bounds__(64) void agg2_k(const ushort_t* __restrict__ h,
                                             const int* __restrict__ row_start,
                                             const ushort_t* __restrict__ csr,
                                             const float* __restrict__ dinv,
                                             const float* __restrict__ bias,
                                             float* __restrict__ out, int n) {
    int i = blockIdx.x;
    int c = threadIdx.x;
    float di = dinv[i];
    float acc = bf2f(h[(size_t)i * 64 + c]) * di * di;
    int j = row_start[i], e1 = row_start[i + 1];
    for (; j + 3 < e1; j += 4) {
        int s0 = csr[j], s1 = csr[j + 1], s2 = csr[j + 2], s3 = csr[j + 3];
        float w0 = dinv[s0] * di, w1 = dinv[s1] * di, w2 = dinv[s2] * di, w3 = dinv[s3] * di;
        float a0 = bf2f(h[(size_t)s0 * 64 + c]), a1 = bf2f(h[(size_t)s1 * 64 + c]);
        float a2 = bf2f(h[(size_t)s2 * 64 + c]), a3 = bf2f(h[(size_t)s3 * 64 + c]);
        acc = fmaf(a0, w0, acc); acc = fmaf(a1, w1, acc);
        acc = fmaf(a2, w2, acc); acc = fmaf(a3, w3, acc);
    }
    for (; j < e1; j++) {
        int s = csr[j];
        acc = fmaf(bf2f(h[(size_t)s * 64 + c]), dinv[s] * di, acc);
    }
    out[(size_t)i * 64 + c] = acc + bias[c];
}

// ---------------- launch ----------------

extern "C" void kernel_launch(void* const* d_in, const int* in_sizes, int n_in,
                              void* d_out, int out_size, void* d_ws, size_t ws_size,
                              hipStream_t stream) {
    const float* x   = (const float*)d_in[0];
    const int*   ei  = (const int*)d_in[1];
    const float* W1  = (const float*)d_in[2];
    const float* b1  = (const float*)d_in[3];
    const float* W2  = (const float*)d_in[4];
    const float* b2  = (const float*)d_in[5];
    float* out = (float*)d_out;

    const int N = in_sizes[0] / 128;
    const int E = in_sizes[1] / 2;
    const int B = (N + 127) >> 7;
    const int* src = ei;
    const int* dst = ei + E;

    char* p = (char*)d_ws;
    auto alloc = [&](size_t bytes) {
        char* q = p;
        p += (bytes + 255) & ~(size_t)255;
        return (void*)q;
    };
    int*      bucket_cnt    = (int*)alloc((size_t)BMAX * 4);
    int*      bucket_base   = (int*)alloc((size_t)(BMAX + 1) * 4);
    int*      bucket_cursor = (int*)alloc((size_t)BMAX * 4);
    float*    dinv          = (float*)alloc((size_t)N * 4);
    int*      row_start     = (int*)alloc((size_t)(N + 1) * 4);
    int*      binned        = (int*)alloc((size_t)E * 4);
    ushort_t* csr           = (ushort_t*)alloc((size_t)E * 2);
    ushort_t* h1            = (ushort_t*)alloc((size_t)N * 128 * 2);
    ushort_t* agg1          = (ushort_t*)alloc((size_t)N * 128 * 2);
    ushort_t* h2            = h1;

    const int nchunks = (E + CHUNK - 1) / CHUNK;

    zero_i_k<<<(B + 255) / 256, 256, 0, stream>>>(bucket_cnt, B);
    hist_k<<<256, 256, 0, stream>>>(dst, bucket_cnt, E, B);
    bscan_k<<<1, 512, 0, stream>>>(bucket_cnt, bucket_base, bucket_cursor, B, E);
    bin_k<<<min(nchunks, 256), 256, 0, stream>>>(src, dst, bucket_cursor, binned, E);
    finalize_k<<<B, 256, 0, stream>>>(binned, bucket_base, dinv, row_start, csr, N, B, E);

    gemm1_k<<<(N + 63) / 64, 256, 0, stream>>>(x, W1, h1, N);
    agg1_k<<<N, 64, 0, stream>>>(h1, row_start, csr, dinv, b1, agg1, N);

    gemm2_k<<<(N + 63) / 64, 256, 0, stream>>>(agg1, W2, h2, N);
    agg2_k<<<N, 64, 0, stream>>>(h2, row_start, csr, dinv, b2, out, N);
}

// Round 17
// 227.857 us; speedup vs baseline: 4.6887x; 1.0020x over previous
//
#include <hip/hip_runtime.h>
#include <hip/hip_bf16.h>

// ============ ROUND 17: 2-edges-per-instruction gather (half-wave split) ============
// R16 (228.3 us): top-5 all harness ws-poison (fixed). My biggest: agg1/agg2
// (~50 us, gather request-rate limited at ~3.7 TB/s effective). Split each wave
// into two 32-lane halves gathering different edges (ushort4/lane = full 256 B
// row per half) -> 2 edges and 512 B in flight per instruction; combine halves
// with __shfl_xor(32). CSR build + MFMA GEMMs unchanged from R16.

typedef unsigned short ushort_t;
typedef __attribute__((ext_vector_type(8))) short bf16x8;
typedef __attribute__((ext_vector_type(4))) float f32x4;

__device__ __forceinline__ float bf2f(ushort_t u) {
    union { unsigned int i; float f; } v;
    v.i = ((unsigned int)u) << 16;
    return v.f;
}

__device__ __forceinline__ ushort_t f2bf(float f) {
    __hip_bfloat16 h = __float2bfloat16(f);
    return *reinterpret_cast<ushort_t*>(&h);
}

#define BMAX 512
#define CHUNK 8192

// ---- CSR build (R15/R16, unchanged) ----
__global__ __launch_bounds__(256) void hist_k(const int* __restrict__ dst,
                                              int* __restrict__ bucket_cnt, int E, int B) {
    __shared__ int h[BMAX];
    int tid = threadIdx.x;
    for (int i = tid; i < B; i += 256) h[i] = 0;
    __syncthreads();
    int stride = gridDim.x * 256;
    for (int e = blockIdx.x * 256 + tid; e < E; e += stride)
        atomicAdd(&h[dst[e] >> 7], 1);
    __syncthreads();
    for (int i = tid; i < B; i += 256)
        if (h[i]) atomicAdd(&bucket_cnt[i], h[i]);
}

__global__ __launch_bounds__(512) void bscan_k(const int* __restrict__ bucket_cnt,
                                               int* __restrict__ bucket_base,
                                               int* __restrict__ bucket_cursor, int B, int E) {
    __shared__ int s[512];
    int tid = threadIdx.x;
    int v = (tid < B) ? bucket_cnt[tid] : 0;
    s[tid] = v;
    __syncthreads();
    for (int off = 1; off < 512; off <<= 1) {
        int t = (tid >= off) ? s[tid - off] : 0;
        __syncthreads();
        s[tid] += t;
        __syncthreads();
    }
    if (tid < B) {
        int ex = s[tid] - v;
        bucket_base[tid] = ex;
        bucket_cursor[tid] = ex;
    }
    if (tid == 0) bucket_base[B] = E;
}

__global__ __launch_bounds__(256) void bin_k(const int* __restrict__ src,
                                             const int* __restrict__ dst,
                                             int* __restrict__ bucket_cursor,
                                             int* __restrict__ binned, int E) {
    __shared__ int lcnt[BMAX], lbase[BMAX], lcur[BMAX];
    int tid = threadIdx.x;
    int nchunks = (E + CHUNK - 1) / CHUNK;
    for (int ch = blockIdx.x; ch < nchunks; ch += gridDim.x) {
        int base = ch * CHUNK;
        int cnt = min(CHUNK, E - base);
        for (int i = tid; i < BMAX; i += 256) lcnt[i] = 0;
        __syncthreads();
        for (int k = tid; k < cnt; k += 256)
            atomicAdd(&lcnt[dst[base + k] >> 7], 1);
        __syncthreads();
        for (int i = tid; i < BMAX; i += 256) {
            int c = lcnt[i];
            if (c) lbase[i] = atomicAdd(&bucket_cursor[i], c);
            lcur[i] = 0;
        }
        __syncthreads();
        for (int k = tid; k < cnt; k += 256) {
            int d = dst[base + k];
            int b = d >> 7;
            int r = atomicAdd(&lcur[b], 1);
            binned[lbase[b] + r] = (src[base + k] << 7) | (d & 127);
        }
        __syncthreads();
    }
}

__global__ __launch_bounds__(256) void finalize_k(const int* __restrict__ binned,
                                                  const int* __restrict__ bucket_base,
                                                  float* __restrict__ dinv,
                                                  int* __restrict__ row_start,
                                                  ushort_t* __restrict__ csr,
                                                  int N, int B, int E) {
    __shared__ int dcnt[128];
    __shared__ int ebase[128];
    __shared__ int sc[128];
    int b = blockIdx.x;
    int tid = threadIdx.x;
    int node0 = b << 7;
    int nn = min(128, N - node0);
    int e0 = bucket_base[b], e1 = bucket_base[b + 1];

    if (tid < 128) dcnt[tid] = 0;
    __syncthreads();
    for (int k = e0 + tid; k < e1; k += 256)
        atomicAdd(&dcnt[binned[k] & 127], 1);
    __syncthreads();
    if (tid < 128) sc[tid] = (tid < nn) ? dcnt[tid] : 0;
    __syncthreads();
    for (int off = 1; off < 128; off <<= 1) {
        int t = 0;
        if (tid < 128 && tid >= off) t = sc[tid - off];
        __syncthreads();
        if (tid < 128) sc[tid] += t;
        __syncthreads();
    }
    if (tid < nn) {
        int deg = dcnt[tid];
        int ex = sc[tid] - deg;
        ebase[tid] = ex;
        int g = node0 + tid;
        dinv[g] = rsqrtf((float)deg + 1.0f);
        row_start[g] = e0 + ex;
        dcnt[tid] = 0;
    }
    if (tid == 0 && b == B - 1) row_start[N] = E;
    __syncthreads();
    for (int k = e0 + tid; k < e1; k += 256) {
        int e = binned[k];
        int low = e & 127;
        int r = atomicAdd(&dcnt[low], 1);
        csr[e0 + ebase[low] + r] = (ushort_t)((unsigned)e >> 7);
    }
}

// ---------------- GEMM1 (MFMA, R16 unchanged) ----------------

__global__ __launch_bounds__(256) void gemm1_k(const float* __restrict__ X,
                                               const float* __restrict__ W,
                                               ushort_t* __restrict__ H, int n) {
    __shared__ ushort_t As[64][136];
    __shared__ ushort_t Bt[128][136];
    const int t = threadIdx.x;
    const int row0 = blockIdx.x * 64;
#pragma unroll
    for (int rep = 0; rep < 8; rep++) {
        int idx = rep * 1024 + t * 4;
        int r = idx >> 7, c = idx & 127;
        int gr = row0 + r;
        float4 v = make_float4(0.f, 0.f, 0.f, 0.f);
        if (gr < n) v = *reinterpret_cast<const float4*>(X + (size_t)gr * 128 + c);
        As[r][c + 0] = f2bf(v.x); As[r][c + 1] = f2bf(v.y);
        As[r][c + 2] = f2bf(v.z); As[r][c + 3] = f2bf(v.w);
    }
#pragma unroll
    for (int rep = 0; rep < 16; rep++) {
        int idx = rep * 1024 + t * 4;
        int k = idx >> 7, nn = idx & 127;
        float4 v = *reinterpret_cast<const float4*>(W + k * 128 + nn);
        Bt[nn + 0][k] = f2bf(v.x); Bt[nn + 1][k] = f2bf(v.y);
        Bt[nn + 2][k] = f2bf(v.z); Bt[nn + 3][k] = f2bf(v.w);
    }
    __syncthreads();
    const int lane = t & 63;
    const int wave = t >> 6;
    const int l15 = lane & 15;
    const int koff = (lane >> 4) * 8;
    f32x4 acc[8] = {};
#pragma unroll
    for (int ks = 0; ks < 4; ks++) {
        int kb = ks * 32 + koff;
        bf16x8 a = *reinterpret_cast<const bf16x8*>(&As[wave * 16 + l15][kb]);
#pragma unroll
        for (int tc = 0; tc < 8; tc++) {
            bf16x8 b = *reinterpret_cast<const bf16x8*>(&Bt[tc * 16 + l15][kb]);
            acc[tc] = __builtin_amdgcn_mfma_f32_16x16x32_bf16(a, b, acc[tc], 0, 0, 0);
        }
    }
    const int rbase = row0 + wave * 16 + (lane >> 4) * 4;
#pragma unroll
    for (int reg = 0; reg < 4; reg++) {
        int gr = rbase + reg;
        if (gr < n) {
#pragma unroll
            for (int tc = 0; tc < 8; tc++)
                H[(size_t)gr * 128 + tc * 16 + l15] = f2bf(acc[tc][reg]);
        }
    }
}

// ---------------- GEMM2 (MFMA, R16 unchanged) ----------------

__global__ __launch_bounds__(256) void gemm2_k(const ushort_t* __restrict__ X,
                                               const float* __restrict__ W,
                                               ushort_t* __restrict__ H, int n) {
    __shared__ ushort_t As[64][136];
    __shared__ ushort_t Bt[64][136];
    const int t = threadIdx.x;
    const int row0 = blockIdx.x * 64;
#pragma unroll
    for (int rep = 0; rep < 8; rep++) {
        int idx = rep * 1024 + t * 4;
        int r = idx >> 7, c = idx & 127;
        int gr = row0 + r;
        ushort4 v = make_ushort4(0, 0, 0, 0);
        if (gr < n) v = *reinterpret_cast<const ushort4*>(X + (size_t)gr * 128 + c);
        As[r][c + 0] = v.x; As[r][c + 1] = v.y; As[r][c + 2] = v.z; As[r][c + 3] = v.w;
    }
#pragma unroll
    for (int rep = 0; rep < 8; rep++) {
        int idx = rep * 1024 + t * 4;
        int k = idx >> 6, nn = idx & 63;
        float4 v = *reinterpret_cast<const float4*>(W + k * 64 + nn);
        Bt[nn + 0][k] = f2bf(v.x); Bt[nn + 1][k] = f2bf(v.y);
        Bt[nn + 2][k] = f2bf(v.z); Bt[nn + 3][k] = f2bf(v.w);
    }
    __syncthreads();
    const int lane = t & 63;
    const int wave = t >> 6;
    const int l15 = lane & 15;
    const int koff = (lane >> 4) * 8;
    f32x4 acc[4] = {};
#pragma unroll
    for (int ks = 0; ks < 4; ks++) {
        int kb = ks * 32 + koff;
        bf16x8 a = *reinterpret_cast<const bf16x8*>(&As[wave * 16 + l15][kb]);
#pragma unroll
        for (int tc = 0; tc < 4; tc++) {
            bf16x8 b = *reinterpret_cast<const bf16x8*>(&Bt[tc * 16 + l15][kb]);
            acc[tc] = __builtin_amdgcn_mfma_f32_16x16x32_bf16(a, b, acc[tc], 0, 0, 0);
        }
    }
    const int rbase = row0 + wave * 16 + (lane >> 4) * 4;
#pragma unroll
    for (int reg = 0; reg < 4; reg++) {
        int gr = rbase + reg;
        if (gr < n) {
#pragma unroll
            for (int tc = 0; tc < 4; tc++)
                H[(size_t)gr * 64 + tc * 16 + l15] = f2bf(acc[tc][reg]);
        }
    }
}

// ---------------- agg1: half-wave pairing, ushort4/lane ----------------
// lanes 0-31 = edge j, lanes 32-63 = edge j+1; lane q=lane&31 owns channels 4q..4q+3.

__global__ __launch_bounds__(64) void agg1_k(const ushort_t* __restrict__ h,
                                             const int* __restrict__ row_start,
                                             const ushort_t* __restrict__ csr,
                                             const float* __restrict__ dinv,
                                             const float* __restrict__ bias,
                                             ushort_t* __restrict__ out, int n) {
    const int i = blockIdx.x;
    const int lane = threadIdx.x;
    const int half = lane >> 5;
    const int q = lane & 31;
    const float di = dinv[i];
    float a0 = 0.f, a1 = 0.f, a2 = 0.f, a3 = 0.f;
    int j = row_start[i];
    const int e1 = row_start[i + 1];
    for (; j + 3 < e1; j += 4) {            // 4 edges per iter, 2 per half
        int jA = j + half, jB = j + 2 + half;
        int sA = csr[jA], sB = csr[jB];
        float wA = dinv[sA] * di, wB = dinv[sB] * di;
        ushort4 vA = *reinterpret_cast<const ushort4*>(h + (size_t)sA * 128 + 4 * q);
        ushort4 vB = *reinterpret_cast<const ushort4*>(h + (size_t)sB * 128 + 4 * q);
        a0 = fmaf(bf2f(vA.x), wA, a0); a1 = fmaf(bf2f(vA.y), wA, a1);
        a2 = fmaf(bf2f(vA.z), wA, a2); a3 = fmaf(bf2f(vA.w), wA, a3);
        a0 = fmaf(bf2f(vB.x), wB, a0); a1 = fmaf(bf2f(vB.y), wB, a1);
        a2 = fmaf(bf2f(vB.z), wB, a2); a3 = fmaf(bf2f(vB.w), wB, a3);
    }
    for (; j < e1; j += 2) {                // remainder (<=3 edges)
        int je = j + half;
        if (je < e1) {
            int s = csr[je];
            float w = dinv[s] * di;
            ushort4 v = *reinterpret_cast<const ushort4*>(h + (size_t)s * 128 + 4 * q);
            a0 = fmaf(bf2f(v.x), w, a0); a1 = fmaf(bf2f(v.y), w, a1);
            a2 = fmaf(bf2f(v.z), w, a2); a3 = fmaf(bf2f(v.w), w, a3);
        }
    }
    a0 += __shfl_xor(a0, 32); a1 += __shfl_xor(a1, 32);
    a2 += __shfl_xor(a2, 32); a3 += __shfl_xor(a3, 32);
    if (half == 0) {
        ushort4 sv = *reinterpret_cast<const ushort4*>(h + (size_t)i * 128 + 4 * q);
        float dd = di * di;
        a0 = fmaf(bf2f(sv.x), dd, a0); a1 = fmaf(bf2f(sv.y), dd, a1);
        a2 = fmaf(bf2f(sv.z), dd, a2); a3 = fmaf(bf2f(sv.w), dd, a3);
        ushort4 o;
        o.x = f2bf(fmaxf(a0 + bias[4 * q + 0], 0.0f));
        o.y = f2bf(fmaxf(a1 + bias[4 * q + 1], 0.0f));
        o.z = f2bf(fmaxf(a2 + bias[4 * q + 2], 0.0f));
        o.w = f2bf(fmaxf(a3 + bias[4 * q + 3], 0.0f));
        *reinterpret_cast<ushort4*>(out + (size_t)i * 128 + 4 * q) = o;
    }
}

// ---------------- agg2: half-wave pairing, ushort2/lane, f32 out ----------------
// lane q owns channels 2q, 2q+1.

__global__ __launch_bounds__(64) void agg2_k(const ushort_t* __restrict__ h,
                                             const int* __restrict__ row_start,
                                             const ushort_t* __restrict__ csr,
                                             const float* __restrict__ dinv,
                                             const float* __restrict__ bias,
                                             float* __restrict__ out, int n) {
    const int i = blockIdx.x;
    const int lane = threadIdx.x;
    const int half = lane >> 5;
    const int q = lane & 31;
    const float di = dinv[i];
    float a0 = 0.f, a1 = 0.f;
    int j = row_start[i];
    const int e1 = row_start[i + 1];
    for (; j + 3 < e1; j += 4) {
        int jA = j + half, jB = j + 2 + half;
        int sA = csr[jA], sB = csr[jB];
        float wA = dinv[sA] * di, wB = dinv[sB] * di;
        ushort2 vA = *reinterpret_cast<const ushort2*>(h + (size_t)sA * 64 + 2 * q);
        ushort2 vB = *reinterpret_cast<const ushort2*>(h + (size_t)sB * 64 + 2 * q);
        a0 = fmaf(bf2f(vA.x), wA, a0); a1 = fmaf(bf2f(vA.y), wA, a1);
        a0 = fmaf(bf2f(vB.x), wB, a0); a1 = fmaf(bf2f(vB.y), wB, a1);
    }
    for (; j < e1; j += 2) {
        int je = j + half;
        if (je < e1) {
            int s = csr[je];
            float w = dinv[s] * di;
            ushort2 v = *reinterpret_cast<const ushort2*>(h + (size_t)s * 64 + 2 * q);
            a0 = fmaf(bf2f(v.x), w, a0); a1 = fmaf(bf2f(v.y), w, a1);
        }
    }
    a0 += __shfl_xor(a0, 32);
    a1 += __shfl_xor(a1, 32);
    if (half == 0) {
        ushort2 sv = *reinterpret_cast<const ushort2*>(h + (size_t)i * 64 + 2 * q);
        float dd = di * di;
        a0 = fmaf(bf2f(sv.x), dd, a0);
        a1 = fmaf(bf2f(sv.y), dd, a1);
        float2 o = make_float2(a0 + bias[2 * q], a1 + bias[2 * q + 1]);
        *reinterpret_cast<float2*>(out + (size_t)i * 64 + 2 * q) = o;
    }
}

// ---------------- launch ----------------

extern "C" void kernel_launch(void* const* d_in, const int* in_sizes, int n_in,
                              void* d_out, int out_size, void* d_ws, size_t ws_size,
                              hipStream_t stream) {
    const float* x   = (const float*)d_in[0];
    const int*   ei  = (const int*)d_in[1];
    const float* W1  = (const float*)d_in[2];
    const float* b1  = (const float*)d_in[3];
    const float* W2  = (const float*)d_in[4];
    const float* b2  = (const float*)d_in[5];
    float* out = (float*)d_out;

    const int N = in_sizes[0] / 128;
    const int E = in_sizes[1] / 2;
    const int B = (N + 127) >> 7;
    const int* src = ei;
    const int* dst = ei + E;

    char* p = (char*)d_ws;
    auto alloc = [&](size_t bytes) {
        char* q = p;
        p += (bytes + 255) & ~(size_t)255;
        return (void*)q;
    };
    int*      bucket_cnt    = (int*)alloc((size_t)BMAX * 4);
    int*      bucket_base   = (int*)alloc((size_t)(BMAX + 1) * 4);
    int*      bucket_cursor = (int*)alloc((size_t)BMAX * 4);
    float*    dinv          = (float*)alloc((size_t)N * 4);
    int*      row_start     = (int*)alloc((size_t)(N + 1) * 4);
    int*      binned        = (int*)alloc((size_t)E * 4);
    ushort_t* csr           = (ushort_t*)alloc((size_t)E * 2);
    ushort_t* h1            = (ushort_t*)alloc((size_t)N * 128 * 2);
    ushort_t* agg1          = (ushort_t*)alloc((size_t)N * 128 * 2);
    ushort_t* h2            = h1;

    const int nchunks = (E + CHUNK - 1) / CHUNK;

    hipMemsetAsync(bucket_cnt, 0, (size_t)B * 4, stream);
    hist_k<<<256, 256, 0, stream>>>(dst, bucket_cnt, E, B);
    bscan_k<<<1, 512, 0, stream>>>(bucket_cnt, bucket_base, bucket_cursor, B, E);
    bin_k<<<min(nchunks, 256), 256, 0, stream>>>(src, dst, bucket_cursor, binned, E);
    finalize_k<<<B, 256, 0, stream>>>(binned, bucket_base, dinv, row_start, csr, N, B, E);

    gemm1_k<<<(N + 63) / 64, 256, 0, stream>>>(x, W1, h1, N);
    agg1_k<<<N, 64, 0, stream>>>(h1, row_start, csr, dinv, b1, agg1, N);

    gemm2_k<<<(N + 63) / 64, 256, 0, stream>>>(agg1, W2, h2, N);
    agg2_k<<<N, 64, 0, stream>>>(h2, row_start, csr, dinv, b2, out, N);
}